// Round 6
// baseline (273.176 us; speedup 1.0000x reference)
//
#include <hip/hip_runtime.h>
#include <math.h>

#define Bb   4
#define Tt   2048
#define DIN  1024
#define DOUT 1024
#define NH   16
#define HD   64
#define BT   (Bb * Tt)   // 8192 tokens

typedef __attribute__((ext_vector_type(8))) short bf16x8;
typedef __attribute__((ext_vector_type(4))) float f32x4;
typedef __attribute__((ext_vector_type(4))) short short4v;

__device__ __forceinline__ short f2bf(float f) {
  union { float f; unsigned u; } v; v.f = f;
  unsigned r = v.u + 0x7FFFu + ((v.u >> 16) & 1u);
  return (short)(r >> 16);
}

// packed f32x2 -> bf16x2 (RNE), single HW op on gfx950
__device__ __forceinline__ unsigned pkbf(float a, float b) {
  unsigned r;
  asm("v_cvt_pk_bf16_f32 %0, %1, %2" : "=v"(r) : "v"(a), "v"(b));
  return r;
}

#define MFMA16(a, b, c) __builtin_amdgcn_mfma_f32_16x16x32_bf16((a), (b), (c), 0, 0, 0)

// async global->LDS, 16B per lane; LDS dest = wave-uniform base + lane*16
__device__ __forceinline__ void gload16(const short* g, short* l) {
  __builtin_amdgcn_global_load_lds(
      (const __attribute__((address_space(1))) void*)g,
      (__attribute__((address_space(3))) void*)l, 16, 0, 0);
}

// ---------------------------------------------------------------------------
// cvt_x: fp32 -> bf16
// ---------------------------------------------------------------------------
__global__ __launch_bounds__(256) void cvt_x(const float* __restrict__ x,
                                             short* __restrict__ xb) {
  const int i = (blockIdx.x * 256 + threadIdx.x) * 4;
  float4 v = *(const float4*)(x + i);
  uint2 o;
  o.x = pkbf(v.x, v.y);
  o.y = pkbf(v.z, v.w);
  *(uint2*)(xb + i) = o;
}

// ---------------------------------------------------------------------------
// cvt_wt: W [K][N] fp32 -> Wt [N][K] bf16 (transpose+convert), 64x64 tiles.
// ---------------------------------------------------------------------------
__global__ __launch_bounds__(256) void cvt_wt(
    const float* __restrict__ W0, const float* __restrict__ W1,
    const float* __restrict__ W2, const float* __restrict__ W3,
    short* __restrict__ O0, short* __restrict__ O1,
    short* __restrict__ O2, short* __restrict__ O3) {
  const float* W = blockIdx.z == 0 ? W0 : blockIdx.z == 1 ? W1
                 : blockIdx.z == 2 ? W2 : W3;
  short* O = blockIdx.z == 0 ? O0 : blockIdx.z == 1 ? O1
           : blockIdx.z == 2 ? O2 : O3;
  __shared__ short t[64][65];
  const int n0 = blockIdx.x * 64, k0 = blockIdx.y * 64;
  const int tid = threadIdx.x;
#pragma unroll
  for (int i = 0; i < 16; ++i) {
    const int e = tid + 256 * i;
    const int k = e >> 6, n = e & 63;
    t[n][k] = f2bf(W[(size_t)(k0 + k) * DOUT + n0 + n]);
  }
  __syncthreads();
#pragma unroll
  for (int i = 0; i < 16; ++i) {
    const int e = tid + 256 * i;
    const int n = e >> 6, k = e & 63;
    O[(size_t)(n0 + n) * DIN + k0 + k] = t[n][k];
  }
}

// ---------------------------------------------------------------------------
// bf16 MFMA GEMM: C[M,N] = A[M,K] @ Bt^T  (Bt[N][K]).
// BM=BN=128, BK=64, 4 waves (2x2), wave tile 64x64.
// global_load_lds w16, linear LDS dest, inverse-swizzled source,
// swizzled frag reads (chunk ^= row&7). QKV mode: z-indexed Bt/C.
// ---------------------------------------------------------------------------
template <bool QKV, bool F32OUT, bool BIAS>
__global__ __launch_bounds__(256) void gemm_bf16(
    const short* __restrict__ A, const short* __restrict__ Bt0,
    const float* __restrict__ bias, void* __restrict__ Cout,
    int M, int N, int K, float qsc) {
  constexpr int BM = 128, BN = 128, BK = 64;
  __shared__ __align__(16) short Asm[BM][BK];   // 16 KB
  __shared__ __align__(16) short Bsm[BN][BK];   // 16 KB

  const short* Bt = Bt0;
  short* Cb16 = (short*)Cout;
  float oscale = 1.0f;
  if (QKV) {
    const int z = blockIdx.z;
    Bt += (size_t)z * N * K;
    Cb16 += (size_t)z * M * N;
    if (z == 0) oscale = qsc;
  }

  const int tid = threadIdx.x;
  const int wid = tid >> 6, lane = tid & 63;
  const int lhi = lane >> 4, llo = lane & 15;
  const int bm = blockIdx.x * BM, bn = blockIdx.y * BN;
  const int wr = (wid >> 1) * 64, wc = (wid & 1) * 64;

  // staging: per issue, wave covers 8 rows x 8 chunks (16B each)
  const int srow = lane >> 3;               // 0..7
  const int sca = ((lane & 7) ^ srow) * 8;  // inverse-swizzled source chunk

  f32x4 acc[4][4];
#pragma unroll
  for (int i = 0; i < 4; ++i)
#pragma unroll
    for (int j = 0; j < 4; ++j)
#pragma unroll
      for (int r = 0; r < 4; ++r) acc[i][j][r] = 0.0f;

  for (int k0 = 0; k0 < K; k0 += BK) {
    __syncthreads();
#pragma unroll
    for (int iss = 0; iss < 4; ++iss) {
      const int ra = wid * 32 + iss * 8 + srow;
      gload16(A + (size_t)(bm + ra) * K + k0 + sca, &Asm[wid * 32 + iss * 8][0]);
      gload16(Bt + (size_t)(bn + ra) * K + k0 + sca, &Bsm[wid * 32 + iss * 8][0]);
    }
    __syncthreads();

#pragma unroll
    for (int ks = 0; ks < 2; ++ks) {
      bf16x8 af[4], bfr[4];
#pragma unroll
      for (int i = 0; i < 4; ++i) {
        const int row = wr + i * 16 + llo;
        af[i] = *(const bf16x8*)&Asm[row][((ks * 4 + lhi) ^ (row & 7)) * 8];
      }
#pragma unroll
      for (int j = 0; j < 4; ++j) {
        const int row = wc + j * 16 + llo;
        bfr[j] = *(const bf16x8*)&Bsm[row][((ks * 4 + lhi) ^ (row & 7)) * 8];
      }
      __builtin_amdgcn_s_setprio(1);
#pragma unroll
      for (int i = 0; i < 4; ++i)
#pragma unroll
        for (int j = 0; j < 4; ++j)
          acc[i][j] = MFMA16(af[i], bfr[j], acc[i][j]);
      __builtin_amdgcn_s_setprio(0);
    }
  }

#pragma unroll
  for (int i = 0; i < 4; ++i)
#pragma unroll
    for (int j = 0; j < 4; ++j)
#pragma unroll
      for (int r = 0; r < 4; ++r) {
        const int row = bm + wr + i * 16 + lhi * 4 + r;
        const int col = bn + wc + j * 16 + llo;
        float v = acc[i][j][r] * oscale;
        if (BIAS) v += bias[col];
        if (F32OUT)
          ((float*)Cout)[(size_t)row * N + col] = v;
        else
          Cb16[(size_t)row * N + col] = f2bf(v);
      }
}

// ---------------------------------------------------------------------------
// Causal flash attention, bf16 MFMA, swapped-QK^T softmax.
// 8 waves x 32 q-rows = 256 q-rows/block; KV tiles of 64, double-buffered.
// V is pre-transposed in HBM (Vt_g[DOUT][BT]) -> linear b128 LDS staging.
// Q pre-scaled by 0.125*log2e in Q-GEMM -> exp2 directly.
// ---------------------------------------------------------------------------
__global__ __launch_bounds__(512, 2) void attn_bf16(
    const short* __restrict__ Q, const short* __restrict__ K,
    const short* __restrict__ Vt_g, short* __restrict__ Ctx) {
  constexpr int LDK = 72;  // 144B rows: 16B-aligned, <=2-way banks (free)
  constexpr int LDV = 72;
  constexpr int LDP = 72;
  __shared__ __align__(16) short Ks[2][64][LDK];  // [kv][d]
  __shared__ __align__(16) short Vt[2][64][LDV];  // [d][kv]
  __shared__ __align__(16) short Ps[8][32][LDP];  // per-wave P [q][kv]

  const int bid = blockIdx.x;
  const int qt = 7 - (bid >> 6);   // longest-first
  const int bh = bid & 63;
  const int b = bh >> 4, h = bh & 15;
  const int tid = threadIdx.x;
  const int wid = tid >> 6, lane = tid & 63;
  const int lhi = lane >> 4, llo = lane & 15;

  const size_t base_bt = (size_t)b * Tt;
  const int headoff = h * HD;
  const int q0 = qt * 256 + wid * 32;

  // Q fragments: qf[rb][kf][e] = Q[q0+rb*16+llo][kf*32+lhi*8+e]
  bf16x8 qf[2][2];
#pragma unroll
  for (int rb = 0; rb < 2; ++rb)
#pragma unroll
    for (int kf = 0; kf < 2; ++kf)
      qf[rb][kf] = *(const bf16x8*)&Q[(base_bt + q0 + rb * 16 + llo) * DOUT +
                                      headoff + kf * 32 + lhi * 8];

  float m_r[2] = {-1e30f, -1e30f}, l_r[2] = {0.0f, 0.0f};
  f32x4 oa[2][4];
#pragma unroll
  for (int rb = 0; rb < 2; ++rb)
#pragma unroll
    for (int j = 0; j < 4; ++j)
#pragma unroll
      for (int r = 0; r < 4; ++r) oa[rb][j][r] = 0.0f;

  // staging maps (512 threads):
  //   K: thread -> kv row (tid>>3), d chunk (tid&7)*8
  //   V^T: thread -> d row (tid>>3), kv chunk (tid&7)*8
  const int skv = tid >> 3;
  const int sd0 = (tid & 7) * 8;

  const int ktmax = qt * 4 + 3;

  // incremental global pointers (advance per tile)
  const short* kgp = K + (base_bt + skv) * DOUT + headoff + sd0;        // tile 0
  const short* vgp = Vt_g + (size_t)(headoff + skv) * BT + base_bt + sd0;

  {  // prologue: stage tile 0 into buf 0
    bf16x8 kreg = *(const bf16x8*)kgp;
    bf16x8 vreg = *(const bf16x8*)vgp;
    *(bf16x8*)&Ks[0][skv][sd0] = kreg;
    *(bf16x8*)&Vt[0][skv][sd0] = vreg;
    kgp += 64 * DOUT;
    vgp += 64;
  }
  __syncthreads();

  for (int kt = 0; kt <= ktmax; ++kt) {
    const int cur = kt & 1;

    bf16x8 kreg, vreg;
    const bool haveNext = kt < ktmax;
    if (haveNext) {
      kreg = *(const bf16x8*)kgp;
      vreg = *(const bf16x8*)vgp;
      kgp += 64 * DOUT;
      vgp += 64;
    }

    if (kt * 64 <= q0 + 31) {
      bf16x8 kf0[4], kf1[4];
#pragma unroll
      for (int j = 0; j < 4; ++j) {
        kf0[j] = *(const bf16x8*)&Ks[cur][j * 16 + llo][lhi * 8];
        kf1[j] = *(const bf16x8*)&Ks[cur][j * 16 + llo][32 + lhi * 8];
      }

#pragma unroll
      for (int rb = 0; rb < 2; ++rb) {
        // S^T: s[j][r] = S[q=llo][kv=j*16+lhi*4+r]
        f32x4 s[4];
        __builtin_amdgcn_s_setprio(1);
#pragma unroll
        for (int j = 0; j < 4; ++j) {
#pragma unroll
          for (int r = 0; r < 4; ++r) s[j][r] = 0.0f;
          s[j] = MFMA16(kf0[j], qf[rb][0], s[j]);
          s[j] = MFMA16(kf1[j], qf[rb][1], s[j]);
        }
        __builtin_amdgcn_s_setprio(0);
        // causal mask
        if (kt * 64 + 63 > q0 + rb * 16) {
          const int kvrel = kt * 64 + lhi * 4 - (q0 + rb * 16 + llo);
#pragma unroll
          for (int j = 0; j < 4; ++j)
#pragma unroll
            for (int r = 0; r < 4; ++r)
              if (kvrel + j * 16 + r > 0) s[j][r] = -1e30f;
        }
        // in-lane row max tree + 2 cross-group shuffles
        float a0 = fmaxf(fmaxf(s[0][0], s[0][1]), fmaxf(s[0][2], s[0][3]));
        float a1 = fmaxf(fmaxf(s[1][0], s[1][1]), fmaxf(s[1][2], s[1][3]));
        float a2 = fmaxf(fmaxf(s[2][0], s[2][1]), fmaxf(s[2][2], s[2][3]));
        float a3 = fmaxf(fmaxf(s[3][0], s[3][1]), fmaxf(s[3][2], s[3][3]));
        float mx = fmaxf(fmaxf(a0, a1), fmaxf(a2, a3));
        mx = fmaxf(mx, __shfl_xor(mx, 16));
        mx = fmaxf(mx, __shfl_xor(mx, 32));
        // defer-max: rescale only when max grew beyond threshold
        if (!__all(mx - m_r[rb] <= 8.0f)) {
          const float mnew = fmaxf(m_r[rb], mx);
          const float al = exp2f(m_r[rb] - mnew);
          m_r[rb] = mnew;
          l_r[rb] *= al;
          float alr[4];
#pragma unroll
          for (int r = 0; r < 4; ++r) alr[r] = __shfl(al, (lhi << 2) | r, 16);
#pragma unroll
          for (int j = 0; j < 4; ++j)
#pragma unroll
            for (int r = 0; r < 4; ++r) oa[rb][j][r] *= alr[r];
        }
        const float mc = m_r[rb];
#pragma unroll
        for (int j = 0; j < 4; ++j)
#pragma unroll
          for (int r = 0; r < 4; ++r) s[j][r] = exp2f(s[j][r] - mc);
        float b0 = (s[0][0] + s[0][1]) + (s[0][2] + s[0][3]);
        float b1 = (s[1][0] + s[1][1]) + (s[1][2] + s[1][3]);
        float b2 = (s[2][0] + s[2][1]) + (s[2][2] + s[2][3]);
        float b3 = (s[3][0] + s[3][1]) + (s[3][2] + s[3][3]);
        float rs = (b0 + b1) + (b2 + b3);
        rs += __shfl_xor(rs, 16);
        rs += __shfl_xor(rs, 32);
        l_r[rb] += rs;
        // pack P -> bf16 pairs -> per-wave LDS [q][kv]
#pragma unroll
        for (int j = 0; j < 4; ++j) {
          uint2 w;
          w.x = pkbf(s[j][0], s[j][1]);
          w.y = pkbf(s[j][2], s[j][3]);
          *(uint2*)&Ps[wid][rb * 16 + llo][j * 16 + lhi * 4] = w;
        }
      }

      // O += P @ V : vf[ks][j][e] = V^T[d=j*16+llo][kv=ks*32+lhi*8+e]
      bf16x8 vfr[2][4];
#pragma unroll
      for (int ks = 0; ks < 2; ++ks)
#pragma unroll
        for (int j = 0; j < 4; ++j)
          vfr[ks][j] = *(const bf16x8*)&Vt[cur][j * 16 + llo][ks * 32 + lhi * 8];
      __builtin_amdgcn_s_setprio(1);
#pragma unroll
      for (int rb = 0; rb < 2; ++rb)
#pragma unroll
        for (int ks = 0; ks < 2; ++ks) {
          bf16x8 paf = *(const bf16x8*)&Ps[wid][rb * 16 + llo][lhi * 8 + ks * 32];
#pragma unroll
          for (int j = 0; j < 4; ++j)
            oa[rb][j] = MFMA16(paf, vfr[ks][j], oa[rb][j]);
        }
      __builtin_amdgcn_s_setprio(0);
    }

    if (haveNext) {
      const int nxt = cur ^ 1;
      *(bf16x8*)&Ks[nxt][skv][sd0] = kreg;
      *(bf16x8*)&Vt[nxt][skv][sd0] = vreg;
    }
    __syncthreads();
  }

  // finalize: redistribute 1/l from llo-layout to (lhi,r)-layout, store
#pragma unroll
  for (int rb = 0; rb < 2; ++rb) {
    const float linv = 1.0f / l_r[rb];
    float lr[4];
#pragma unroll
    for (int r = 0; r < 4; ++r) lr[r] = __shfl(linv, (lhi << 2) | r, 16);
#pragma unroll
    for (int j = 0; j < 4; ++j)
#pragma unroll
      for (int r = 0; r < 4; ++r) {
        const int row = q0 + rb * 16 + lhi * 4 + r;
        const int col = headoff + j * 16 + llo;
        Ctx[(base_bt + row) * DOUT + col] = f2bf(oa[rb][j][r] * lr[r]);
      }
  }
}

// ---------------------------------------------------------------------------
extern "C" void kernel_launch(void* const* d_in, const int* in_sizes, int n_in,
                              void* d_out, int out_size, void* d_ws, size_t ws_size,
                              hipStream_t stream) {
  const float* x  = (const float*)d_in[0];
  const float* Wq = (const float*)d_in[1];
  const float* Wk = (const float*)d_in[2];
  const float* Wv = (const float*)d_in[3];
  const float* Wo = (const float*)d_in[4];
  const float* bo = (const float*)d_in[5];
  float* out = (float*)d_out;

  const size_t NTD = (size_t)Bb * Tt * DOUT;
  const size_t WSZ = (size_t)DIN * DOUT;
  short* xb  = (short*)d_ws;
  short* Wqt = xb + NTD;
  short* Wkt = Wqt + WSZ;   // Wqt/Wkt contiguous (QK z-indexing)
  short* Wvt = Wkt + WSZ;
  short* Wot = Wvt + WSZ;
  short* Qb  = Wot + WSZ;   // Qb/Kb contiguous (QK z-indexing)
  short* Kb  = Qb + NTD;
  short* Vtb = Kb + NTD;    // V^T [DOUT][BT]
  short* Cb  = Vtb + NTD;

  const int M = Bb * Tt;  // 8192
  const float qscale = 0.125f * 1.44269504089f;  // 1/sqrt(HD) * log2(e)

  cvt_x<<<dim3(NTD / 1024), 256, 0, stream>>>(x, xb);
  cvt_wt<<<dim3(16, 16, 4), 256, 0, stream>>>(Wq, Wk, Wv, Wo, Wqt, Wkt, Wvt, Wot);

  // Q (pre-scaled) and K projections
  gemm_bf16<true, false, false><<<dim3(64, 8, 2), 256, 0, stream>>>(
      xb, Wqt, nullptr, Qb, M, DOUT, DIN, qscale);
  // V^T projection: C[d][tok] = sum_k Wvt[d][k] * xb[tok][k]
  gemm_bf16<false, false, false><<<dim3(8, 64), 256, 0, stream>>>(
      Wvt, xb, nullptr, Vtb, DOUT, M, DIN, 1.0f);

  attn_bf16<<<dim3(512), 512, 0, stream>>>(Qb, Kb, Vtb, Cb);

  gemm_bf16<false, true, true><<<dim3(64, 8), 256, 0, stream>>>(
      Cb, Wot, bo, out, M, DOUT, DOUT, 1.0f);
}